// Round 6
// baseline (607.936 us; speedup 1.0000x reference)
//
#include <hip/hip_runtime.h>
#include <hip/hip_bf16.h>

// Fused Interaction Estimator, v6: whole-W-in-LDS, two-pass, barrier-free loop.
// Each main kernel: 256 blocks x 512 threads (8 waves), LDS = one branch's
// packed bf16 W (exactly 128 KB). ONE __syncthreads after the W load, then a
// completely barrier-free loop: each wave owns 16 complete rows per job
// (acc = 64 VGPRs -- fits the observed ~128-reg cap with room for prefetch),
// LN/dots are within-wave 16-lane shuffle reductions.
// g-pass parks g_align (bf16) in the hi-half of each output row's 1KB slot in
// d_out (rows are only ever touched by their owning wave; lo-col writes can't
// clobber, hi-slot reads happen before hi-col writes). gdot (393KB) in d_ws.

typedef float f32x4 __attribute__((ext_vector_type(4)));
typedef short short8 __attribute__((ext_vector_type(8)));
typedef unsigned int u32;

#define D_DIM 256

union S8 { short8 s; u32 u[4]; };

__device__ __forceinline__ u32 f2bfu(float x) {   // RNE f32->bf16 (finite)
  u32 u = __float_as_uint(x);
  return (u + 0x7FFFu + ((u >> 16) & 1u)) >> 16;
}
__device__ __forceinline__ u32 pk2(float a, float b) { return f2bfu(a) | (f2bfu(b) << 16); }
__device__ __forceinline__ float bflo(u32 u) { return __uint_as_float(u << 16); }
__device__ __forceinline__ float bfhi(u32 u) { return __uint_as_float(u & 0xffff0000u); }
__device__ __forceinline__ float sigm(float x) { return 1.0f / (1.0f + __expf(-x)); }

// load 8 consecutive f32, pack to bf16 MFMA A-fragment
__device__ __forceinline__ short8 ldA(const float* __restrict__ p) {
  float4 lo = *(const float4*)p;
  float4 hi = *(const float4*)(p + 4);
  S8 r;
  r.u[0] = pk2(lo.x, lo.y);
  r.u[1] = pk2(lo.z, lo.w);
  r.u[2] = pk2(hi.x, hi.y);
  r.u[3] = pk2(hi.z, hi.w);
  return r.s;
}

// ---------------- prep: pack W (f32 [k][m]) into bf16 fragment order ----------------
// chunk = (t*16 + c)*64 + l holds 8 bf16: B[k = t*32 + (l>>4)*8 + j][m = c*16 + (l&15)]
// (t-major so the main kernel's 16 ct ds_read offsets fit the 16-bit immediate)
__global__ __launch_bounds__(256) void pack_w_kernel(const float* __restrict__ Wg,
                                                     const float* __restrict__ Wp,
                                                     unsigned short* __restrict__ outp) {
  int b = blockIdx.x;
  const float* W = (b < 32) ? Wg : Wp;
  unsigned short* o = outp + (b < 32 ? 0 : 65536);
  int chunk = (b & 31) * 256 + threadIdx.x;   // 0..8191
  int l = chunk & 63;
  int c = (chunk >> 6) & 15;
  int t = chunk >> 10;
  int m = c * 16 + (l & 15);
  int kb = t * 32 + ((l >> 4) << 3);
  short8 v;
#pragma unroll
  for (int j = 0; j < 8; ++j) v[j] = (short)f2bfu(W[(kb + j) * 256 + m]);
  *(short8*)(o + (size_t)chunk * 8) = v;
}

// ---------------- shared core: 16 rows x 256 cols: gemm + bias + LN + ReLU + dot ----------------
__device__ __forceinline__ void branch_core(
    const float* __restrict__ A,              // &feat[r0*256]
    const unsigned short* __restrict__ WB,    // LDS, packed fragments
    const float* __restrict__ bias, const float* __restrict__ gam,
    const float* __restrict__ bet, const float* __restrict__ wa,
    int lane, f32x4 acc[16], float dotv[4])
{
  const int cl = lane & 15, kg = lane >> 4;
  const float* ab = A + (size_t)cl * D_DIM + kg * 8;

#pragma unroll
  for (int ct = 0; ct < 16; ++ct) acc[ct] = {0.f, 0.f, 0.f, 0.f};

#pragma unroll
  for (int t = 0; t < 8; ++t) {
    short8 a = ldA(ab + t * 32);
    const unsigned short* wb = WB + t * 8192 + lane * 8;
#pragma unroll
    for (int ct = 0; ct < 16; ++ct) {
      short8 b = *(const short8*)(wb + ct * 512);   // ds_read_b128, imm offsets
      acc[ct] = __builtin_amdgcn_mfma_f32_16x16x32_bf16(a, b, acc[ct], 0, 0, 0);
    }
  }

  // bias + per-row stats (lane holds rows kg*4+rr, col ct*16+cl)
  float s[4] = {0,0,0,0}, q[4] = {0,0,0,0};
#pragma unroll
  for (int ct = 0; ct < 16; ++ct) {
    float bb = bias[ct * 16 + cl];
#pragma unroll
    for (int rr = 0; rr < 4; ++rr) {
      float y = acc[ct][rr] + bb;
      acc[ct][rr] = y;
      s[rr] += y; q[rr] += y * y;
    }
  }
  float mu[4], rs[4];
#pragma unroll
  for (int rr = 0; rr < 4; ++rr) {
    float ss = s[rr], qq = q[rr];
#pragma unroll
    for (int m = 1; m < 16; m <<= 1) { ss += __shfl_xor(ss, m, 64); qq += __shfl_xor(qq, m, 64); }
    float mm = ss * (1.0f / 256.0f);
    float vv = fmaxf(qq * (1.0f / 256.0f) - mm * mm, 0.0f);
    mu[rr] = mm;
    rs[rr] = rsqrtf(vv + 1e-5f);
  }

  // LN + ReLU (in place) + dot(align, wa)
  float dp[4] = {0,0,0,0};
#pragma unroll
  for (int ct = 0; ct < 16; ++ct) {
    float gg = gam[ct * 16 + cl], bb = bet[ct * 16 + cl], ww = wa[ct * 16 + cl];
#pragma unroll
    for (int rr = 0; rr < 4; ++rr) {
      float al = (acc[ct][rr] - mu[rr]) * rs[rr] * gg + bb;
      al = fmaxf(al, 0.0f);
      acc[ct][rr] = al;
      dp[rr] += al * ww;
    }
  }
#pragma unroll
  for (int rr = 0; rr < 4; ++rr) {
    float d = dp[rr];
#pragma unroll
    for (int m = 1; m < 16; m <<= 1) d += __shfl_xor(d, m, 64);
    dotv[rr] = d;
  }
}

// ---------------- pass 1: g branch ----------------
__global__ __launch_bounds__(512, 2) void g_pass(
    const float* __restrict__ gfeat, const unsigned short* __restrict__ wpkg,
    const float* __restrict__ bg, const float* __restrict__ glng,
    const float* __restrict__ glnb, const float* __restrict__ wap,
    u32* __restrict__ out_u32, float* __restrict__ gdot)
{
  __shared__ unsigned short WB[65536];   // 128 KB
  const int tid = threadIdx.x;
  {
    const short8* src = (const short8*)wpkg;
    short8* dst = (short8*)WB;
#pragma unroll
    for (int i = 0; i < 16; ++i) dst[i * 512 + tid] = src[i * 512 + tid];
  }
  __syncthreads();   // the only barrier

  const int lane = tid & 63, w = tid >> 6;
  const int cl = lane & 15, kg = lane >> 4;
  const int base = blockIdx.x * 384 + w * 16;

  for (int it = 0; it < 3; ++it) {
    const int r0 = base + it * 128;
    f32x4 acc[16];
    float dotv[4];
    branch_core(gfeat + (size_t)r0 * D_DIM, WB, bg, glng, glnb, wap, lane, acc, dotv);

    if (cl == 0) {
#pragma unroll
      for (int rr = 0; rr < 4; ++rr) gdot[r0 + kg * 4 + rr] = dotv[rr];
    }
    // park alignG bf16 in hi-half of each of this job's 16 row-slots:
    // lane's fragment ct -> row-slot (r0+ct), u32 offset 128 + lane*2
#pragma unroll
    for (int ct = 0; ct < 16; ++ct) {
      uint2 v;
      v.x = pk2(acc[ct][0], acc[ct][1]);
      v.y = pk2(acc[ct][2], acc[ct][3]);
      *(uint2*)(out_u32 + 256 * (size_t)(r0 + ct) + 128 + lane * 2) = v;
    }
  }
}

// ---------------- pass 2: p branch + fusion ----------------
__global__ __launch_bounds__(512, 2) void p_pass(
    const float* __restrict__ pfeat, const unsigned short* __restrict__ wpkp,
    const float* __restrict__ bp, const float* __restrict__ plng,
    const float* __restrict__ plnb, const float* __restrict__ wag,
    const float* __restrict__ bag, const float* __restrict__ bap,
    const float* __restrict__ gdot, float* __restrict__ outf)
{
  __shared__ unsigned short WB[65536];
  const int tid = threadIdx.x;
  {
    const short8* src = (const short8*)wpkp;
    short8* dst = (short8*)WB;
#pragma unroll
    for (int i = 0; i < 16; ++i) dst[i * 512 + tid] = src[i * 512 + tid];
  }
  __syncthreads();   // the only barrier

  const int lane = tid & 63, w = tid >> 6;
  const int cl = lane & 15, kg = lane >> 4;
  const int base = blockIdx.x * 384 + w * 16;
  const float vbag = bag[0], vbap = bap[0];
  u32* out_u32 = (u32*)outf;

  for (int it = 0; it < 3; ++it) {
    const int r0 = base + it * 128;
    f32x4 acc[16];
    float pdot[4];
    branch_core(pfeat + (size_t)r0 * D_DIM, WB, bp, plng, plnb, wag, lane, acc, pdot);

    float gd[4];
#pragma unroll
    for (int rr = 0; rr < 4; ++rr) gd[rr] = gdot[r0 + kg * 4 + rr];

    // phase 1: ct 0..7 -> writes land in cols<128 (lo halves), never clobber parked slots
#pragma unroll
    for (int ct = 0; ct < 8; ++ct) {
      uint2 gv = *(const uint2*)(out_u32 + 256 * (size_t)(r0 + ct) + 128 + lane * 2);
      float ga[4] = { bflo(gv.x), bfhi(gv.x), bflo(gv.y), bfhi(gv.y) };
#pragma unroll
      for (int rr = 0; rr < 4; ++rr) {
        float pa = acc[ct][rr];
        float geno = sigm(ga[rr] * pdot[rr] + vbag);
        float path = sigm(pa * gd[rr] + vbap);
        outf[(size_t)(r0 + kg * 4 + rr) * D_DIM + ct * 16 + cl] = pa * path + ga[rr] * geno;
      }
    }
    // phase 2: pre-read remaining slots (rows r0+8..15), THEN write hi cols
    uint2 gvh[8];
#pragma unroll
    for (int ct = 8; ct < 16; ++ct)
      gvh[ct - 8] = *(const uint2*)(out_u32 + 256 * (size_t)(r0 + ct) + 128 + lane * 2);
#pragma unroll
    for (int ct = 8; ct < 16; ++ct) {
      uint2 gv = gvh[ct - 8];
      float ga[4] = { bflo(gv.x), bfhi(gv.x), bflo(gv.y), bfhi(gv.y) };
#pragma unroll
      for (int rr = 0; rr < 4; ++rr) {
        float pa = acc[ct][rr];
        float geno = sigm(ga[rr] * pdot[rr] + vbag);
        float path = sigm(pa * gd[rr] + vbap);
        outf[(size_t)(r0 + kg * 4 + rr) * D_DIM + ct * 16 + cl] = pa * path + ga[rr] * geno;
      }
    }
  }
}

extern "C" void kernel_launch(void* const* d_in, const int* in_sizes, int n_in,
                              void* d_out, int out_size, void* d_ws, size_t ws_size,
                              hipStream_t stream) {
  const float* gfeat = (const float*)d_in[0];
  const float* pfeat = (const float*)d_in[1];
  const float* Wg   = (const float*)d_in[2];
  const float* bg   = (const float*)d_in[3];
  const float* glng = (const float*)d_in[4];
  const float* glnb = (const float*)d_in[5];
  const float* Wp   = (const float*)d_in[6];
  const float* bp   = (const float*)d_in[7];
  const float* plng = (const float*)d_in[8];
  const float* plnb = (const float*)d_in[9];
  const float* wag  = (const float*)d_in[10];
  const float* bag  = (const float*)d_in[11];
  const float* wap  = (const float*)d_in[12];
  const float* bap  = (const float*)d_in[13];

  unsigned short* wpk = (unsigned short*)d_ws;            // 256 KB packed Wg|Wp
  float* gdot = (float*)((char*)d_ws + 262144);           // 393 KB

  hipLaunchKernelGGL(pack_w_kernel, dim3(64), dim3(256), 0, stream, Wg, Wp, wpk);

  hipLaunchKernelGGL(g_pass, dim3(256), dim3(512), 0, stream,
                     gfeat, wpk, bg, glng, glnb, wap, (u32*)d_out, gdot);

  hipLaunchKernelGGL(p_pass, dim3(256), dim3(512), 0, stream,
                     pfeat, wpk + 65536, bp, plng, plnb, wag, bag, bap,
                     gdot, (float*)d_out);
}

// Round 7
// 235.880 us; speedup vs baseline: 2.5773x; 2.5773x over previous
//
#include <hip/hip_runtime.h>
#include <hip/hip_bf16.h>

// Fused Interaction Estimator, v7: 16-wave blocks, persistent W in registers
// (64 VGPR/wave), fragment-packed A in LDS (zero bank conflicts).
// 256 blocks x 1024 threads; 12 row-tiles (32 rows) per block.
// Each wave owns 16 output cols; W frags for both branches live in regs,
// loaded once per block. Inner loop: 16 ds_read_b128 + 16 MFMA per branch,
// no global loads. LN across waves via padded LDS partials + 512-thread
// shuffle-reduce phases. A-tile loads issue one phase before their LDS write.

typedef float f32x4 __attribute__((ext_vector_type(4)));
typedef short short8 __attribute__((ext_vector_type(8)));
typedef unsigned int u32;

#define D_DIM 256
#define NW 16
#define TPB 12

union S8 { short8 s; u32 u[4]; };

__device__ __forceinline__ u32 f2bfu(float x) {   // RNE f32->bf16 (finite)
  u32 u = __float_as_uint(x);
  return (u + 0x7FFFu + ((u >> 16) & 1u)) >> 16;
}
__device__ __forceinline__ u32 pk2(float a, float b) { return f2bfu(a) | (f2bfu(b) << 16); }
__device__ __forceinline__ float sigm(float x) { return 1.0f / (1.0f + __expf(-x)); }

// ---------------- prep: pack W (f32 [k][m]) into bf16 fragment order, t-major ----------------
// chunk = (t*16 + c)*64 + l holds 8 bf16: B[k = t*32 + (l>>4)*8 + j][m = c*16 + (l&15)]
__global__ __launch_bounds__(256) void pack_w_kernel(const float* __restrict__ Wg,
                                                     const float* __restrict__ Wp,
                                                     unsigned short* __restrict__ outp) {
  int b = blockIdx.x;
  const float* W = (b < 32) ? Wg : Wp;
  unsigned short* o = outp + (b < 32 ? 0 : 65536);
  int chunk = (b & 31) * 256 + threadIdx.x;   // 0..8191
  int l = chunk & 63;
  int c = (chunk >> 6) & 15;
  int t = chunk >> 10;
  int m = c * 16 + (l & 15);
  int kb = t * 32 + ((l >> 4) << 3);
  short8 v;
#pragma unroll
  for (int j = 0; j < 8; ++j) v[j] = (short)f2bfu(W[(kb + j) * 256 + m]);
  *(short8*)(o + (size_t)chunk * 8) = v;
}

// ---------------- main ----------------

// pack 8 f32 (2 float4) -> short8 and store to frag-packed LDS chunk `tid`
__device__ __forceinline__ void stageWrite(const float4& a, const float4& b,
                                           unsigned short* buf, int tid) {
  S8 r;
  r.u[0] = pk2(a.x, a.y);
  r.u[1] = pk2(a.z, a.w);
  r.u[2] = pk2(b.x, b.y);
  r.u[3] = pk2(b.z, b.w);
  *(short8*)(buf + (size_t)tid * 8) = r.s;   // linear: zero conflicts
}

__device__ __forceinline__ void gemm16(f32x4 acc[2], const unsigned short* buf,
                                       const short8 wf[8], int lane) {
  acc[0] = {0.f, 0.f, 0.f, 0.f};
  acc[1] = {0.f, 0.f, 0.f, 0.f};
  const unsigned short* bp = buf + lane * 8;
#pragma unroll
  for (int t = 0; t < 8; ++t) {
    short8 a0 = *(const short8*)(bp + (t * 2 + 0) * 512);   // ds_read_b128, imm offset
    short8 a1 = *(const short8*)(bp + (t * 2 + 1) * 512);
    acc[0] = __builtin_amdgcn_mfma_f32_16x16x32_bf16(a0, wf[t], acc[0], 0, 0, 0);
    acc[1] = __builtin_amdgcn_mfma_f32_16x16x32_bf16(a1, wf[t], acc[1], 0, 0, 0);
  }
}

// bias add (in place) + write per-wave row partials (sum, sumsq)
__device__ __forceinline__ void statsW(f32x4 acc[2], float bv,
                                       float smS[32][17], float smQ[32][17],
                                       int cl, int kg, int w) {
#pragma unroll
  for (int rt = 0; rt < 2; ++rt)
#pragma unroll
    for (int r = 0; r < 4; ++r) {
      float y = acc[rt][r] + bv;
      acc[rt][r] = y;
      float s = y, q = y * y;
#pragma unroll
      for (int m = 1; m < 16; m <<= 1) { s += __shfl_xor(s, m, 64); q += __shfl_xor(q, m, 64); }
      if (cl == 0) {
        int row = rt * 16 + kg * 4 + r;
        smS[row][w] = s;
        smQ[row][w] = q;
      }
    }
}

// 1024 threads: reduce 16 wave-partials per row -> smMu, smQm (both /256)
__device__ __forceinline__ void statsReduce(int tid, const float smS[32][17],
                                            const float smQ[32][17],
                                            float smMu[32], float smQm[32]) {
  if (tid < 512) {
    int row = tid >> 4, k = tid & 15;
    float v = smS[row][k];
#pragma unroll
    for (int m = 1; m < 16; m <<= 1) v += __shfl_xor(v, m, 64);
    if (k == 0) smMu[row] = v * (1.0f / 256.0f);
  } else {
    int j = tid - 512;
    int row = j >> 4, k = j & 15;
    float v = smQ[row][k];
#pragma unroll
    for (int m = 1; m < 16; m <<= 1) v += __shfl_xor(v, m, 64);
    if (k == 0) smQm[row] = v * (1.0f / 256.0f);
  }
}

// LN + ReLU -> outAl ; per-wave dot(align, wa) partials -> smRed
__device__ __forceinline__ void applyW(const f32x4 acc[2], f32x4 outAl[2],
                                       float gv, float tv, float wv,
                                       const float smMu[32], const float smQm[32],
                                       float smRed[32][17], int cl, int kg, int w) {
#pragma unroll
  for (int rt = 0; rt < 2; ++rt)
#pragma unroll
    for (int r = 0; r < 4; ++r) {
      int row = rt * 16 + kg * 4 + r;
      float mu = smMu[row];
      float var = fmaxf(smQm[row] - mu * mu, 0.0f);
      float rs = rsqrtf(var + 1e-5f);
      float al = (acc[rt][r] - mu) * rs * gv + tv;
      al = fmaxf(al, 0.0f);
      outAl[rt][r] = al;
      float d = al * wv;
#pragma unroll
      for (int m = 1; m < 16; m <<= 1) d += __shfl_xor(d, m, 64);
      if (cl == 0) smRed[row][w] = d;
    }
}

__device__ __forceinline__ void redReduce(int tid, const float smRed[32][17], float smD[32]) {
  if (tid < 512) {
    int row = tid >> 4, k = tid & 15;
    float v = smRed[row][k];
#pragma unroll
    for (int m = 1; m < 16; m <<= 1) v += __shfl_xor(v, m, 64);
    if (k == 0) smD[row] = v;
  }
}

__global__ __launch_bounds__(1024, 4) void fused_main(
    const float* __restrict__ gfeat, const float* __restrict__ pfeat,
    const float* __restrict__ bg, const float* __restrict__ glng, const float* __restrict__ glnb,
    const float* __restrict__ bp, const float* __restrict__ plng, const float* __restrict__ plnb,
    const float* __restrict__ wag, const float* __restrict__ bag,
    const float* __restrict__ wap, const float* __restrict__ bap,
    const unsigned short* __restrict__ wpk,
    float* __restrict__ outp)
{
  __shared__ unsigned short bG[8192];   // 16 KB, fragment-packed bf16 A (g)
  __shared__ unsigned short bP[8192];   // 16 KB (p)
  __shared__ float smS[32][17], smQ[32][17], smRed[32][17];
  __shared__ float smMu[32], smQm[32], smGd[32], smPd[32];

  const int tid = threadIdx.x;
  const int lane = tid & 63;
  const int w = tid >> 6;               // wave id == staging chunk group
  const int cl = lane & 15, kg = lane >> 4;

  // staging map (thread == fragment chunk): wave w = (t*2 + rt)
  const int s_row = (w & 1) * 16 + cl;            // 0..31
  const int s_kf  = (w >> 1) * 32 + kg * 8;       // f32 index within row

  // persistent W fragments: wave w covers cols w*16..w*16+15 (ct = w)
  short8 wfg[8], wfp[8];
  {
    const short8* g8 = (const short8*)wpk;
    const short8* p8 = (const short8*)(wpk + 65536);
#pragma unroll
    for (int t = 0; t < 8; ++t) {
      int idx = (t * 16 + w) * 64 + lane;
      wfg[t] = g8[idx];
      wfp[t] = p8[idx];
    }
  }

  // per-lane scalar params (col = w*16 + cl)
  const int col = w * 16 + cl;
  const float bgv = bg[col],  ggv = glng[col], gbv = glnb[col], wapv = wap[col];
  const float bpv = bp[col],  pgv = plng[col], pbv = plnb[col], wagv = wag[col];
  const float vbag = bag[0], vbap = bap[0];

  // issue first tile's loads (held in regs; landed well before ph1 write)
  const size_t blk0 = (size_t)blockIdx.x * TPB * 32;
  float4 rGa, rGb, rPa, rPb;
  {
    const float* gp = gfeat + (blk0 + s_row) * D_DIM + s_kf;
    const float* pp = pfeat + (blk0 + s_row) * D_DIM + s_kf;
    rGa = *(const float4*)gp;  rGb = *(const float4*)(gp + 4);
    rPa = *(const float4*)pp;  rPb = *(const float4*)(pp + 4);
  }

  f32x4 acc[2], alignG[2];

  for (int i = 0; i < TPB; ++i) {
    const size_t row0 = blk0 + (size_t)i * 32;

    // ph1: write g(i) to LDS
    stageWrite(rGa, rGb, bG, tid);
    __syncthreads();   // #1

    // ph2: issue g(i+1); gemm g; stats partials
    if (i + 1 < TPB) {
      const float* np = gfeat + (row0 + 32 + s_row) * D_DIM + s_kf;
      rGa = *(const float4*)np;  rGb = *(const float4*)(np + 4);
    }
    gemm16(acc, bG, wfg, lane);
    statsW(acc, bgv, smS, smQ, cl, kg, w);
    __syncthreads();   // #2

    statsReduce(tid, smS, smQ, smMu, smQm);
    __syncthreads();   // #3

    applyW(acc, alignG, ggv, gbv, wapv, smMu, smQm, smRed, cl, kg, w);
    __syncthreads();   // #4

    redReduce(tid, smRed, smGd);
    stageWrite(rPa, rPb, bP, tid);      // p(i) -> LDS (bP reads ended at prev #6)
    __syncthreads();   // #5

    // ph6: issue p(i+1); gemm p; stats partials
    if (i + 1 < TPB) {
      const float* np = pfeat + (row0 + 32 + s_row) * D_DIM + s_kf;
      rPa = *(const float4*)np;  rPb = *(const float4*)(np + 4);
    }
    gemm16(acc, bP, wfp, lane);
    statsW(acc, bpv, smS, smQ, cl, kg, w);
    __syncthreads();   // #6

    statsReduce(tid, smS, smQ, smMu, smQm);
    __syncthreads();   // #7

    applyW(acc, acc, pgv, pbv, wagv, smMu, smQm, smRed, cl, kg, w);  // acc := alignP
    __syncthreads();   // #8

    redReduce(tid, smRed, smPd);
    __syncthreads();   // #9

    // ph10: fusion + store (no trailing barrier; see hazard notes)
#pragma unroll
    for (int rt = 0; rt < 2; ++rt)
#pragma unroll
      for (int r = 0; r < 4; ++r) {
        int row = rt * 16 + kg * 4 + r;
        float gr = smGd[row];   // g_align . wa_p
        float pr = smPd[row];   // p_align . wa_g
        float ga = alignG[rt][r];
        float pa = acc[rt][r];
        float geno = sigm(ga * pr + vbag);
        float path = sigm(pa * gr + vbap);
        outp[(row0 + row) * D_DIM + col] = pa * path + ga * geno;
      }
    // hazards across seam: bG rewrite (next ph1) -- last read was ph2 (#2)  [safe]
    // smS/smQ rewrite next ph2 (after next #1) -- last read ph7 (#7)       [safe]
    // smGd/smPd read here; rewritten next ph5/ph9 behind >=4 barriers      [safe]
  }
}

extern "C" void kernel_launch(void* const* d_in, const int* in_sizes, int n_in,
                              void* d_out, int out_size, void* d_ws, size_t ws_size,
                              hipStream_t stream) {
  const float* gfeat = (const float*)d_in[0];
  const float* pfeat = (const float*)d_in[1];
  const float* Wg   = (const float*)d_in[2];
  const float* bg   = (const float*)d_in[3];
  const float* glng = (const float*)d_in[4];
  const float* glnb = (const float*)d_in[5];
  const float* Wp   = (const float*)d_in[6];
  const float* bp   = (const float*)d_in[7];
  const float* plng = (const float*)d_in[8];
  const float* plnb = (const float*)d_in[9];
  const float* wag  = (const float*)d_in[10];
  const float* bag  = (const float*)d_in[11];
  const float* wap  = (const float*)d_in[12];
  const float* bap  = (const float*)d_in[13];
  float* outp = (float*)d_out;
  unsigned short* wpk = (unsigned short*)d_ws;   // 256 KB packed Wg|Wp

  hipLaunchKernelGGL(pack_w_kernel, dim3(64), dim3(256), 0, stream, Wg, Wp, wpk);

  int nrows = in_sizes[0] / D_DIM;          // 98304
  int nblocks = nrows / (32 * TPB);         // 256
  hipLaunchKernelGGL(fused_main, dim3(nblocks), dim3(1024), 0, stream,
                     gfeat, pfeat, bg, glng, glnb, bp, plng, plnb,
                     wag, bag, wap, bap, wpk, outp);
}

// Round 9
// 163.582 us; speedup vs baseline: 3.7164x; 1.4420x over previous
//
#include <hip/hip_runtime.h>
#include <hip/hip_bf16.h>

// Fused Interaction Estimator, v9: v1 numerics core (4 waves x 4 ct, proven)
// + global_load_lds front-loaded staging + raw s_barrier with counted waits.
// 3072 blocks x 256 threads, one 32-row tile per block.
// Both tiles' f32 data (64 KB) issue as DMAs at block entry (zero VGPRs);
// pre-gemm-g barrier waits vmcnt(8) (g only), bufP waits vmcnt(0) at B2 after
// the entire g-phase covered its latency. Mid barriers wait lgkmcnt(0) only.
// LDS keeps raw f32, XOR-swizzled via the GLOBAL source address (DMA dest is
// linear); f32->bf16 conversion happens in-gemm via v_cvt_pk (overlaps MFMA).

typedef float f32x4 __attribute__((ext_vector_type(4)));
typedef short short8 __attribute__((ext_vector_type(8)));
typedef unsigned int u32;

#define D_DIM 256
#define ROWS 32
#define NW 4

union S8 { short8 s; u32 u[4]; };

__device__ __forceinline__ u32 f2bfu(float x) {   // RNE f32->bf16 (finite)
  u32 u = __float_as_uint(x);
  return (u + 0x7FFFu + ((u >> 16) & 1u)) >> 16;
}
__device__ __forceinline__ float sigm(float x) { return 1.0f / (1.0f + __expf(-x)); }

__device__ __forceinline__ u32 pk2c(float a, float b) {   // -> v_cvt_pk_bf16_f32
  __hip_bfloat162 h = __float22bfloat162_rn(float2{a, b});
  union { __hip_bfloat162 h; u32 u; } cv;
  cv.h = h;
  return cv.u;   // low 16 = a, high 16 = b
}

// ---------------- prep: pack W (f32 [k][m] row-major) into bf16 MFMA B-fragment order ----
// chunk = c*512 + t*64 + l holds 8 bf16: B[k = t*32 + (l>>4)*8 + j][m = c*16 + (l&15)]
__global__ __launch_bounds__(256) void pack_w_kernel(const float* __restrict__ Wg,
                                                     const float* __restrict__ Wp,
                                                     unsigned short* __restrict__ outp) {
  int b = blockIdx.x;
  const float* W = (b < 32) ? Wg : Wp;
  unsigned short* o = outp + (b < 32 ? 0 : 65536);
  int chunk = (b & 31) * 256 + threadIdx.x;
  int c = chunk >> 9;
  int rest = chunk & 511;
  int t = rest >> 6;
  int l = rest & 63;
  int m = c * 16 + (l & 15);
  int kb = t * 32 + ((l >> 4) << 3);
  short8 v;
#pragma unroll
  for (int j = 0; j < 8; ++j) v[j] = (short)f2bfu(W[(kb + j) * 256 + m]);
  *(short8*)(o + (size_t)chunk * 8) = v;
}

// ---------------- main fused kernel ----------------

// issue 8 row-DMAs for wave w into lbuf (f32, source-swizzled at 16B granules)
__device__ __forceinline__ void stage_dma(const float* __restrict__ src, float* lbuf,
                                          int w, int lane) {
#pragma unroll
  for (int j = 0; j < 8; ++j) {
    int r = w * 8 + j;
    const float* gp = src + r * D_DIM + ((lane ^ (r & 7)) << 2);   // 16B granule XOR
    float* lp = lbuf + r * D_DIM;                                  // wave-uniform, linear
    __builtin_amdgcn_global_load_lds(
        (const __attribute__((address_space(1))) u32*)gp,
        (__attribute__((address_space(3))) u32*)lp, 16, 0, 0);
  }
}

__device__ __forceinline__ void barrier_fence() {
  __builtin_amdgcn_s_barrier();
  asm volatile("" ::: "memory");
}

// read A-fragment (rt, t) from swizzled f32 LDS tile and convert to bf16
__device__ __forceinline__ short8 readAf32(const float* buf, int rt, int t, int lane) {
  const int cl = lane & 15, kg = lane >> 4;
  const int r = rt * 16 + cl;
  const int s = r & 7;
  const int c16 = t * 8 + kg * 2;   // 16B-granule index within the row
  const char* base = (const char*)buf + r * 1024;
  float4 x = *(const float4*)(base + ((c16 ^ s) << 4));
  float4 y = *(const float4*)(base + (((c16 + 1) ^ s) << 4));
  S8 rr;
  rr.u[0] = pk2c(x.x, x.y);
  rr.u[1] = pk2c(x.z, x.w);
  rr.u[2] = pk2c(y.x, y.y);
  rr.u[3] = pk2c(y.z, y.w);
  return rr.s;
}

// wave w owns cols w*64 .. w*64+63 (ct = w*4 + c)
__device__ __forceinline__ void gemm4(f32x4 acc[2][4], const float* buf,
                                      const short8* __restrict__ wb, int lane, int w) {
  const int bbase = w * 2048 + lane;
#pragma unroll
  for (int t = 0; t < 8; ++t) {
    short8 a0 = readAf32(buf, 0, t, lane);
    short8 a1 = readAf32(buf, 1, t, lane);
#pragma unroll
    for (int c = 0; c < 4; ++c) {
      short8 bfr = wb[bbase + c * 512 + t * 64];
      acc[0][c] = __builtin_amdgcn_mfma_f32_16x16x32_bf16(a0, bfr, acc[0][c], 0, 0, 0);
      acc[1][c] = __builtin_amdgcn_mfma_f32_16x16x32_bf16(a1, bfr, acc[1][c], 0, 0, 0);
    }
  }
}

__device__ __forceinline__ void statsPhase(f32x4 acc[2][4], const float* __restrict__ bias,
                                           float smSum[NW][32], float smSq[NW][32],
                                           int lane, int w) {
  float bv[4];
#pragma unroll
  for (int c = 0; c < 4; ++c) bv[c] = bias[w * 64 + c * 16 + (lane & 15)];
#pragma unroll
  for (int rt = 0; rt < 2; ++rt) {
#pragma unroll
    for (int r = 0; r < 4; ++r) {
      float s = 0.f, qq = 0.f;
#pragma unroll
      for (int c = 0; c < 4; ++c) {
        float y = acc[rt][c][r] + bv[c];
        acc[rt][c][r] = y;
        s += y; qq += y * y;
      }
#pragma unroll
      for (int m = 1; m < 16; m <<= 1) {
        s += __shfl_xor(s, m, 64);
        qq += __shfl_xor(qq, m, 64);
      }
      if ((lane & 15) == 0) {
        int row = rt * 16 + ((lane >> 4) << 2) + r;
        smSum[w][row] = s;
        smSq[w][row] = qq;
      }
    }
  }
}

__device__ __forceinline__ void applyPhase(f32x4 acc[2][4], f32x4 outAl[2][4],
                                           const float* __restrict__ gam, const float* __restrict__ bet,
                                           const float* __restrict__ wa,
                                           const float smSum[NW][32], const float smSq[NW][32],
                                           float smRed[NW][32], int lane, int w) {
  int cb = w * 64 + (lane & 15);
  float gv[4], tv[4], wv[4];
#pragma unroll
  for (int c = 0; c < 4; ++c) {
    gv[c] = gam[cb + c * 16];
    tv[c] = bet[cb + c * 16];
    wv[c] = wa[cb + c * 16];
  }
#pragma unroll
  for (int rt = 0; rt < 2; ++rt) {
#pragma unroll
    for (int r = 0; r < 4; ++r) {
      int row = rt * 16 + ((lane >> 4) << 2) + r;
      float s = 0.f, qq = 0.f;
#pragma unroll
      for (int k = 0; k < NW; ++k) { s += smSum[k][row]; qq += smSq[k][row]; }
      float mu = s * (1.0f / 256.0f);
      float var = fmaxf(qq * (1.0f / 256.0f) - mu * mu, 0.0f);
      float rs = rsqrtf(var + 1e-5f);
      float dp = 0.f;
#pragma unroll
      for (int c = 0; c < 4; ++c) {
        float a = (acc[rt][c][r] - mu) * rs * gv[c] + tv[c];
        a = fmaxf(a, 0.0f);
        outAl[rt][c][r] = a;
        dp += a * wv[c];
      }
#pragma unroll
      for (int m = 1; m < 16; m <<= 1) dp += __shfl_xor(dp, m, 64);
      if ((lane & 15) == 0) smRed[w][row] = dp;
    }
  }
}

__global__ __launch_bounds__(256, 2) void fused_main(
    const float* __restrict__ gfeat, const float* __restrict__ pfeat,
    const float* __restrict__ bg, const float* __restrict__ glng, const float* __restrict__ glnb,
    const float* __restrict__ bp, const float* __restrict__ plng, const float* __restrict__ plnb,
    const float* __restrict__ wag, const float* __restrict__ bag,
    const float* __restrict__ wap, const float* __restrict__ bap,
    const unsigned short* __restrict__ wpk,
    float* __restrict__ outp)
{
  __shared__ float bufG[ROWS * D_DIM];   // 32 KB raw f32, source-swizzled
  __shared__ float bufP[ROWS * D_DIM];   // 32 KB
  __shared__ float smSum[NW][32], smSq[NW][32], smRedG[NW][32], smRedP[NW][32];

  const int tid = threadIdx.x;
  const int lane = tid & 63;
  const int w = tid >> 6;
  const size_t row0 = (size_t)blockIdx.x * ROWS;

  const short8* wbg = (const short8*)wpk;
  const short8* wbp = (const short8*)(wpk + 65536);

  // front-load ALL HBM traffic for this block: 8 g-DMAs then 8 p-DMAs per wave
  stage_dma(gfeat + row0 * D_DIM, bufG, w, lane);
  stage_dma(pfeat + row0 * D_DIM, bufP, w, lane);

  // wait g only (oldest 8); p stays in flight under the whole g-phase
  asm volatile("s_waitcnt vmcnt(8)" ::: "memory");
  barrier_fence();                       // B0: bufG staged

  f32x4 accG[2][4];
#pragma unroll
  for (int rt = 0; rt < 2; ++rt)
#pragma unroll
    for (int c = 0; c < 4; ++c) accG[rt][c] = {0.f, 0.f, 0.f, 0.f};
  gemm4(accG, bufG, wbg, lane, w);
  statsPhase(accG, bg, smSum, smSq, lane, w);
  asm volatile("s_waitcnt lgkmcnt(0)" ::: "memory");
  barrier_fence();                       // B1: statsG visible (lgkm only)

  f32x4 alignG[2][4];
  applyPhase(accG, alignG, glng, glnb, wap, smSum, smSq, smRedG, lane, w);
  asm volatile("s_waitcnt vmcnt(0) lgkmcnt(0)" ::: "memory");
  barrier_fence();                       // B2: bufP staged; smRedG visible; smSum reads done

  f32x4 accP[2][4];
#pragma unroll
  for (int rt = 0; rt < 2; ++rt)
#pragma unroll
    for (int c = 0; c < 4; ++c) accP[rt][c] = {0.f, 0.f, 0.f, 0.f};
  gemm4(accP, bufP, wbp, lane, w);
  statsPhase(accP, bp, smSum, smSq, lane, w);   // smSum rewrite: applyG reads ended at B2
  asm volatile("s_waitcnt lgkmcnt(0)" ::: "memory");
  barrier_fence();                       // B3: statsP visible

  applyPhase(accP, accP, plng, plnb, wag, smSum, smSq, smRedP, lane, w);  // acc := alignP
  asm volatile("s_waitcnt lgkmcnt(0)" ::: "memory");
  barrier_fence();                       // B4: smRedP visible

  // fusion + store
  const float vbag = bag[0], vbap = bap[0];
#pragma unroll
  for (int rt = 0; rt < 2; ++rt) {
#pragma unroll
    for (int r = 0; r < 4; ++r) {
      int row = rt * 16 + ((lane >> 4) << 2) + r;
      float gr = 0.f, pr = 0.f;
#pragma unroll
      for (int k = 0; k < NW; ++k) { gr += smRedG[k][row]; pr += smRedP[k][row]; }
      float* orow = outp + (row0 + row) * D_DIM + w * 64 + (lane & 15);
#pragma unroll
      for (int c = 0; c < 4; ++c) {
        float ga = alignG[rt][c][r];
        float pa = accP[rt][c][r];
        float geno = sigm(ga * pr + vbag);
        float path = sigm(pa * gr + vbap);
        orow[c * 16] = pa * path + ga * geno;
      }
    }
  }
}

extern "C" void kernel_launch(void* const* d_in, const int* in_sizes, int n_in,
                              void* d_out, int out_size, void* d_ws, size_t ws_size,
                              hipStream_t stream) {
  const float* gfeat = (const float*)d_in[0];
  const float* pfeat = (const float*)d_in[1];
  const float* Wg   = (const float*)d_in[2];
  const float* bg   = (const float*)d_in[3];
  const float* glng = (const float*)d_in[4];
  const float* glnb = (const float*)d_in[5];
  const float* Wp   = (const float*)d_in[6];
  const float* bp   = (const float*)d_in[7];
  const float* plng = (const float*)d_in[8];
  const float* plnb = (const float*)d_in[9];
  const float* wag  = (const float*)d_in[10];
  const float* bag  = (const float*)d_in[11];
  const float* wap  = (const float*)d_in[12];
  const float* bap  = (const float*)d_in[13];
  float* outp = (float*)d_out;
  unsigned short* wpk = (unsigned short*)d_ws;   // 256 KB used

  hipLaunchKernelGGL(pack_w_kernel, dim3(64), dim3(256), 0, stream, Wg, Wp, wpk);

  int nrows = in_sizes[0] / D_DIM;   // 98304
  int nblocks = nrows / ROWS;        // 3072
  hipLaunchKernelGGL(fused_main, dim3(nblocks), dim3(256), 0, stream,
                     gfeat, pfeat, bg, glng, glnb, bp, plng, plnb,
                     wag, bag, wap, bap, wpk, outp);
}

// Round 10
// 132.803 us; speedup vs baseline: 4.5777x; 1.2318x over previous
//
#include <hip/hip_runtime.h>
#include <hip/hip_bf16.h>

// Fused Interaction Estimator, v10: v9 + single-buffer LDS (34 KB -> 4
// blocks/CU) + batched gemm loads (2 A-windows + 8 B-windows per gemm).
// 3072 blocks x 256 threads, one 32-row tile per block, 4 blocks/CU pinned
// via __launch_bounds__(256,4) (VGPR cap 128).
// g-tile DMA'd to LDS at entry; p-tile DMA issues right after B1 (g reads
// done) into the SAME buffer, latency covered by applyG + 3 other blocks.
// Counted s_waitcnt + raw s_barrier (no vmcnt(0) drains mid-pipeline).

typedef float f32x4 __attribute__((ext_vector_type(4)));
typedef short short8 __attribute__((ext_vector_type(8)));
typedef unsigned int u32;

#define D_DIM 256
#define ROWS 32
#define NW 4

union S8 { short8 s; u32 u[4]; };

__device__ __forceinline__ u32 f2bfu(float x) {   // RNE f32->bf16 (finite)
  u32 u = __float_as_uint(x);
  return (u + 0x7FFFu + ((u >> 16) & 1u)) >> 16;
}
__device__ __forceinline__ float sigm(float x) { return 1.0f / (1.0f + __expf(-x)); }

__device__ __forceinline__ u32 pk2c(float a, float b) {   // -> v_cvt_pk_bf16_f32
  __hip_bfloat162 h = __float22bfloat162_rn(float2{a, b});
  union { __hip_bfloat162 h; u32 u; } cv;
  cv.h = h;
  return cv.u;
}

// ---------------- prep: pack W (f32 [k][m] row-major) into bf16 MFMA B-fragment order ----
// chunk = c*512 + t*64 + l holds 8 bf16: B[k = t*32 + (l>>4)*8 + j][m = c*16 + (l&15)]
__global__ __launch_bounds__(256) void pack_w_kernel(const float* __restrict__ Wg,
                                                     const float* __restrict__ Wp,
                                                     unsigned short* __restrict__ outp) {
  int b = blockIdx.x;
  const float* W = (b < 32) ? Wg : Wp;
  unsigned short* o = outp + (b < 32 ? 0 : 65536);
  int chunk = (b & 31) * 256 + threadIdx.x;
  int c = chunk >> 9;
  int rest = chunk & 511;
  int t = rest >> 6;
  int l = rest & 63;
  int m = c * 16 + (l & 15);
  int kb = t * 32 + ((l >> 4) << 3);
  short8 v;
#pragma unroll
  for (int j = 0; j < 8; ++j) v[j] = (short)f2bfu(W[(kb + j) * 256 + m]);
  *(short8*)(o + (size_t)chunk * 8) = v;
}

// ---------------- main fused kernel ----------------

// issue 8 row-DMAs for wave w into lbuf (f32, source-swizzled at 16B granules)
__device__ __forceinline__ void stage_dma(const float* __restrict__ src, float* lbuf,
                                          int w, int lane) {
#pragma unroll
  for (int j = 0; j < 8; ++j) {
    int r = w * 8 + j;
    const float* gp = src + r * D_DIM + ((lane ^ (r & 7)) << 2);   // 16B granule XOR
    float* lp = lbuf + r * D_DIM;                                  // wave-uniform, linear
    __builtin_amdgcn_global_load_lds(
        (const __attribute__((address_space(1))) u32*)gp,
        (__attribute__((address_space(3))) u32*)lp, 16, 0, 0);
  }
}

__device__ __forceinline__ void barrier_fence() {
  __builtin_amdgcn_s_barrier();
  asm volatile("" ::: "memory");
}

// read A-fragment (rt, t) from swizzled f32 LDS tile and convert to bf16
__device__ __forceinline__ short8 readAf32(const float* buf, int rt, int t, int lane) {
  const int cl = lane & 15, kg = lane >> 4;
  const int r = rt * 16 + cl;
  const int s = r & 7;
  const int c16 = t * 8 + kg * 2;
  const char* base = (const char*)buf + r * 1024;
  float4 x = *(const float4*)(base + ((c16 ^ s) << 4));
  float4 y = *(const float4*)(base + (((c16 + 1) ^ s) << 4));
  S8 rr;
  rr.u[0] = pk2c(x.x, x.y);
  rr.u[1] = pk2c(x.z, x.w);
  rr.u[2] = pk2c(y.x, y.y);
  rr.u[3] = pk2c(y.z, y.w);
  return rr.s;
}

// batched gemm: per half, burst-read 8 A-frags; per ct, burst-load 4 B-frags.
__device__ __forceinline__ void gemm4(f32x4 acc[2][4], const float* buf,
                                      const short8* __restrict__ wb, int lane, int w) {
  const int bbase = w * 2048 + lane;
#pragma unroll
  for (int h = 0; h < 2; ++h) {
    short8 a0[4], a1[4];
#pragma unroll
    for (int tt = 0; tt < 4; ++tt) {
      a0[tt] = readAf32(buf, 0, h * 4 + tt, lane);
      a1[tt] = readAf32(buf, 1, h * 4 + tt, lane);
    }
#pragma unroll
    for (int c = 0; c < 4; ++c) {
      short8 bf[4];
#pragma unroll
      for (int tt = 0; tt < 4; ++tt) bf[tt] = wb[bbase + c * 512 + (h * 4 + tt) * 64];
#pragma unroll
      for (int tt = 0; tt < 4; ++tt) {
        acc[0][c] = __builtin_amdgcn_mfma_f32_16x16x32_bf16(a0[tt], bf[tt], acc[0][c], 0, 0, 0);
        acc[1][c] = __builtin_amdgcn_mfma_f32_16x16x32_bf16(a1[tt], bf[tt], acc[1][c], 0, 0, 0);
      }
    }
  }
}

__device__ __forceinline__ void statsPhase(f32x4 acc[2][4], const float* __restrict__ bias,
                                           float smSum[NW][32], float smSq[NW][32],
                                           int lane, int w) {
  float bv[4];
#pragma unroll
  for (int c = 0; c < 4; ++c) bv[c] = bias[w * 64 + c * 16 + (lane & 15)];
#pragma unroll
  for (int rt = 0; rt < 2; ++rt) {
#pragma unroll
    for (int r = 0; r < 4; ++r) {
      float s = 0.f, qq = 0.f;
#pragma unroll
      for (int c = 0; c < 4; ++c) {
        float y = acc[rt][c][r] + bv[c];
        acc[rt][c][r] = y;
        s += y; qq += y * y;
      }
#pragma unroll
      for (int m = 1; m < 16; m <<= 1) {
        s += __shfl_xor(s, m, 64);
        qq += __shfl_xor(qq, m, 64);
      }
      if ((lane & 15) == 0) {
        int row = rt * 16 + ((lane >> 4) << 2) + r;
        smSum[w][row] = s;
        smSq[w][row] = qq;
      }
    }
  }
}

__device__ __forceinline__ void applyPhase(f32x4 acc[2][4], f32x4 outAl[2][4],
                                           const float* __restrict__ gam, const float* __restrict__ bet,
                                           const float* __restrict__ wa,
                                           const float smSum[NW][32], const float smSq[NW][32],
                                           float smRed[NW][32], int lane, int w) {
  int cb = w * 64 + (lane & 15);
  float gv[4], tv[4], wv[4];
#pragma unroll
  for (int c = 0; c < 4; ++c) {
    gv[c] = gam[cb + c * 16];
    tv[c] = bet[cb + c * 16];
    wv[c] = wa[cb + c * 16];
  }
#pragma unroll
  for (int rt = 0; rt < 2; ++rt) {
#pragma unroll
    for (int r = 0; r < 4; ++r) {
      int row = rt * 16 + ((lane >> 4) << 2) + r;
      float s = 0.f, qq = 0.f;
#pragma unroll
      for (int k = 0; k < NW; ++k) { s += smSum[k][row]; qq += smSq[k][row]; }
      float mu = s * (1.0f / 256.0f);
      float var = fmaxf(qq * (1.0f / 256.0f) - mu * mu, 0.0f);
      float rs = rsqrtf(var + 1e-5f);
      float dp = 0.f;
#pragma unroll
      for (int c = 0; c < 4; ++c) {
        float a = (acc[rt][c][r] - mu) * rs * gv[c] + tv[c];
        a = fmaxf(a, 0.0f);
        outAl[rt][c][r] = a;
        dp += a * wv[c];
      }
#pragma unroll
      for (int m = 1; m < 16; m <<= 1) dp += __shfl_xor(dp, m, 64);
      if ((lane & 15) == 0) smRed[w][row] = dp;
    }
  }
}

__global__ __launch_bounds__(256, 4) void fused_main(
    const float* __restrict__ gfeat, const float* __restrict__ pfeat,
    const float* __restrict__ bg, const float* __restrict__ glng, const float* __restrict__ glnb,
    const float* __restrict__ bp, const float* __restrict__ plng, const float* __restrict__ plnb,
    const float* __restrict__ wag, const float* __restrict__ bag,
    const float* __restrict__ wap, const float* __restrict__ bap,
    const unsigned short* __restrict__ wpk,
    float* __restrict__ outp)
{
  __shared__ float bufA[ROWS * D_DIM];   // 32 KB raw f32, source-swizzled; g then p
  __shared__ float smSum[NW][32], smSq[NW][32], smRedG[NW][32], smRedP[NW][32];

  const int tid = threadIdx.x;
  const int lane = tid & 63;
  const int w = tid >> 6;
  const size_t row0 = (size_t)blockIdx.x * ROWS;

  const short8* wbg = (const short8*)wpk;
  const short8* wbp = (const short8*)(wpk + 65536);

  // stage g tile (8 DMAs/wave, zero VGPR)
  stage_dma(gfeat + row0 * D_DIM, bufA, w, lane);
  asm volatile("s_waitcnt vmcnt(0)" ::: "memory");
  barrier_fence();                       // B0: g staged

  f32x4 accG[2][4];
#pragma unroll
  for (int rt = 0; rt < 2; ++rt)
#pragma unroll
    for (int c = 0; c < 4; ++c) accG[rt][c] = {0.f, 0.f, 0.f, 0.f};
  gemm4(accG, bufA, wbg, lane, w);
  statsPhase(accG, bg, smSum, smSq, lane, w);
  asm volatile("s_waitcnt lgkmcnt(0)" ::: "memory");
  barrier_fence();                       // B1: statsG visible; all g-reads of bufA done

  // p tile into the SAME buffer; latency covered by applyG + other blocks
  stage_dma(pfeat + row0 * D_DIM, bufA, w, lane);

  f32x4 alignG[2][4];
  applyPhase(accG, alignG, glng, glnb, wap, smSum, smSq, smRedG, lane, w);
  asm volatile("s_waitcnt vmcnt(0) lgkmcnt(0)" ::: "memory");
  barrier_fence();                       // B2: p staged; smRedG visible; applyG smSum reads done

  f32x4 accP[2][4];
#pragma unroll
  for (int rt = 0; rt < 2; ++rt)
#pragma unroll
    for (int c = 0; c < 4; ++c) accP[rt][c] = {0.f, 0.f, 0.f, 0.f};
  gemm4(accP, bufA, wbp, lane, w);
  statsPhase(accP, bp, smSum, smSq, lane, w);   // smSum rewrite: applyG reads ended at B2
  asm volatile("s_waitcnt lgkmcnt(0)" ::: "memory");
  barrier_fence();                       // B3: statsP visible

  applyPhase(accP, accP, plng, plnb, wag, smSum, smSq, smRedP, lane, w);  // acc := alignP
  asm volatile("s_waitcnt lgkmcnt(0)" ::: "memory");
  barrier_fence();                       // B4: smRedP visible

  // fusion + store
  const float vbag = bag[0], vbap = bap[0];
#pragma unroll
  for (int rt = 0; rt < 2; ++rt) {
#pragma unroll
    for (int r = 0; r < 4; ++r) {
      int row = rt * 16 + ((lane >> 4) << 2) + r;
      float gr = 0.f, pr = 0.f;
#pragma unroll
      for (int k = 0; k < NW; ++k) { gr += smRedG[k][row]; pr += smRedP[k][row]; }
      float* orow = outp + (row0 + row) * D_DIM + w * 64 + (lane & 15);
#pragma unroll
      for (int c = 0; c < 4; ++c) {
        float ga = alignG[rt][c][r];
        float pa = accP[rt][c][r];
        float geno = sigm(ga * pr + vbag);
        float path = sigm(pa * gr + vbap);
        orow[c * 16] = pa * path + ga * geno;
      }
    }
  }
}

extern "C" void kernel_launch(void* const* d_in, const int* in_sizes, int n_in,
                              void* d_out, int out_size, void* d_ws, size_t ws_size,
                              hipStream_t stream) {
  const float* gfeat = (const float*)d_in[0];
  const float* pfeat = (const float*)d_in[1];
  const float* Wg   = (const float*)d_in[2];
  const float* bg   = (const float*)d_in[3];
  const float* glng = (const float*)d_in[4];
  const float* glnb = (const float*)d_in[5];
  const float* Wp   = (const float*)d_in[6];
  const float* bp   = (const float*)d_in[7];
  const float* plng = (const float*)d_in[8];
  const float* plnb = (const float*)d_in[9];
  const float* wag  = (const float*)d_in[10];
  const float* bag  = (const float*)d_in[11];
  const float* wap  = (const float*)d_in[12];
  const float* bap  = (const float*)d_in[13];
  float* outp = (float*)d_out;
  unsigned short* wpk = (unsigned short*)d_ws;   // 256 KB used

  hipLaunchKernelGGL(pack_w_kernel, dim3(64), dim3(256), 0, stream, Wg, Wp, wpk);

  int nrows = in_sizes[0] / D_DIM;   // 98304
  int nblocks = nrows / ROWS;        // 3072
  hipLaunchKernelGGL(fused_main, dim3(nblocks), dim3(256), 0, stream,
                     gfeat, pfeat, bg, glng, glnb, bp, plng, plnb,
                     wag, bag, wap, bap, wpk, outp);
}